// Round 8
// baseline (623.164 us; speedup 1.0000x reference)
//
#include <hip/hip_runtime.h>
#include <stdint.h>

#define D  64
#define D2 128
#define CHUNK 1024

// ---------------------------------------------------------------------------
// Histogram of dst, 2 edges/thread. cnt must be pre-zeroed.
// ---------------------------------------------------------------------------
__global__ __launch_bounds__(256) void k_hist(
    const int* __restrict__ ei, int* __restrict__ cnt, int E)
{
    int i2 = blockIdx.x * 256 + threadIdx.x;
    int e0 = i2 * 2;
    if (e0 >= E) return;
    int2 d = ((const int2*)ei)[i2];
    atomicAdd(&cnt[d.x], 1);
    if (e0 + 1 < E) atomicAdd(&cnt[d.y], 1);
}

// ---------------------------------------------------------------------------
__global__ __launch_bounds__(256) void k_scan1(
    const int* __restrict__ cnt, int* __restrict__ offs,
    int* __restrict__ bsum, int N)
{
    __shared__ int sd[256];
    int t    = threadIdx.x;
    int i0   = blockIdx.x * CHUNK + t * 4;
    int v0 = (i0 + 0 < N) ? cnt[i0 + 0] : 0;
    int v1 = (i0 + 1 < N) ? cnt[i0 + 1] : 0;
    int v2 = (i0 + 2 < N) ? cnt[i0 + 2] : 0;
    int v3 = (i0 + 3 < N) ? cnt[i0 + 3] : 0;
    int s = v0 + v1 + v2 + v3;
    sd[t] = s;
    __syncthreads();
    for (int off = 1; off < 256; off <<= 1) {
        int x = (t >= off) ? sd[t - off] : 0;
        __syncthreads();
        sd[t] += x;
        __syncthreads();
    }
    int excl = sd[t] - s;
    if (t == 255) bsum[blockIdx.x] = sd[255];
    if (i0 + 0 < N) offs[i0 + 0] = excl;
    if (i0 + 1 < N) offs[i0 + 1] = excl + v0;
    if (i0 + 2 < N) offs[i0 + 2] = excl + v0 + v1;
    if (i0 + 3 < N) offs[i0 + 3] = excl + v0 + v1 + v2;
}

__global__ void k_scan2(const int* __restrict__ bsum, int* __restrict__ boff, int NB)
{
    __shared__ int sd[128];
    int t = threadIdx.x;
    int v = (t < NB) ? bsum[t] : 0;
    sd[t] = v;
    __syncthreads();
    for (int off = 1; off < 128; off <<= 1) {
        int x = (t >= off) ? sd[t - off] : 0;
        __syncthreads();
        sd[t] += x;
        __syncthreads();
    }
    if (t < NB) boff[t] = sd[t] - v;
}

__global__ __launch_bounds__(256) void k_scan3(
    int* __restrict__ offs, int* __restrict__ cnt,
    const int* __restrict__ boff, int N, int E)
{
    int i = blockIdx.x * 256 + threadIdx.x;
    if (i < N) {
        int o = offs[i] + boff[i / CHUNK];
        offs[i] = o;
        cnt[i]  = o;
    }
    if (i == 0) offs[N] = E;
}

// ---------------------------------------------------------------------------
// Scatter, 2 edges/thread: payload[pos] = (src<<8) | code.
// ---------------------------------------------------------------------------
__global__ __launch_bounds__(256) void k_scatter(
    const int* __restrict__ ei, const int* __restrict__ ef,
    int* __restrict__ cursor, int* __restrict__ payload, int E)
{
    int i2 = blockIdx.x * 256 + threadIdx.x;
    int e0 = i2 * 2;
    if (e0 >= E) return;
    int2 d = ((const int2*)ei)[i2];
    int2 s = ((const int2*)(ei + E))[i2];
    int2 q0 = ((const int2*)ef)[3 * i2 + 0];   // e0.f0, e0.f1
    int2 q1 = ((const int2*)ef)[3 * i2 + 1];   // e0.f2, e1.f0
    int2 q2 = ((const int2*)ef)[3 * i2 + 2];   // e1.f1, e1.f2
    int code0 = q0.x * 12 + q0.y * 2 + q1.x;
    int pos0 = atomicAdd(&cursor[d.x], 1);
    payload[pos0] = (s.x << 8) | code0;
    if (e0 + 1 < E) {
        int code1 = q1.y * 12 + q2.x * 2 + q2.y;
        int pos1 = atomicAdd(&cursor[d.y], 1);
        payload[pos1] = (s.y << 8) | code1;
    }
}

// ---------------------------------------------------------------------------
// Gather-reduce + fuse h = (1+eps)*nf + msg. One wave per node, lane=feature.
// Payload: ONE coalesced batch load per 64 edges; per-edge distribution via
// readlane (-> SGPR, address math on SALU). 8-way MLP unroll, 2 accumulators.
// Embedding-sum table built in LDS.
// ---------------------------------------------------------------------------
__global__ __launch_bounds__(256) void k_reduce(
    const float* __restrict__ nf,
    const int* __restrict__ offs,
    const int* __restrict__ payload,
    const float* __restrict__ be0, const float* __restrict__ be1,
    const float* __restrict__ be2,
    const float* __restrict__ epsp,
    float* __restrict__ h, int N)
{
    __shared__ float sE[60 * D];   // 15 KB
    int tid = threadIdx.x;
    for (int i = tid; i < 60 * D; i += 256) {
        int c = i >> 6, l = i & 63;
        int f0 = c / 12, r = c % 12;
        sE[i] = be0[f0 * D + l] + be1[(r >> 1) * D + l] + be2[(r & 1) * D + l];
    }
    __syncthreads();

    int n = (blockIdx.x * 256 + tid) >> 6;
    int l = tid & 63;
    if (n >= N) return;

    int s0 = offs[n];
    int s1 = offs[n + 1];
    float acc0 = 0.0f, acc1 = 0.0f;
    for (int jb = s0; jb < s1; jb += 64) {
        int u = (jb + l < s1) ? payload[jb + l] : 0;   // coalesced batch
        int m = s1 - jb; if (m > 64) m = 64;
        int t = 0;
        for (; t + 8 <= m; t += 8) {
            int u0 = __builtin_amdgcn_readlane(u, t + 0);
            int u1 = __builtin_amdgcn_readlane(u, t + 1);
            int u2 = __builtin_amdgcn_readlane(u, t + 2);
            int u3 = __builtin_amdgcn_readlane(u, t + 3);
            int u4 = __builtin_amdgcn_readlane(u, t + 4);
            int u5 = __builtin_amdgcn_readlane(u, t + 5);
            int u6 = __builtin_amdgcn_readlane(u, t + 6);
            int u7 = __builtin_amdgcn_readlane(u, t + 7);
            float x0 = nf[((u0 >> 8) << 6) + l];
            float x1 = nf[((u1 >> 8) << 6) + l];
            float x2 = nf[((u2 >> 8) << 6) + l];
            float x3 = nf[((u3 >> 8) << 6) + l];
            float x4 = nf[((u4 >> 8) << 6) + l];
            float x5 = nf[((u5 >> 8) << 6) + l];
            float x6 = nf[((u6 >> 8) << 6) + l];
            float x7 = nf[((u7 >> 8) << 6) + l];
            float e0 = sE[((u0 & 255) << 6) + l];
            float e1 = sE[((u1 & 255) << 6) + l];
            float e2 = sE[((u2 & 255) << 6) + l];
            float e3 = sE[((u3 & 255) << 6) + l];
            float e4 = sE[((u4 & 255) << 6) + l];
            float e5 = sE[((u5 & 255) << 6) + l];
            float e6 = sE[((u6 & 255) << 6) + l];
            float e7 = sE[((u7 & 255) << 6) + l];
            acc0 += fmaxf(x0 + e0, 0.0f) + fmaxf(x1 + e1, 0.0f)
                  + fmaxf(x2 + e2, 0.0f) + fmaxf(x3 + e3, 0.0f);
            acc1 += fmaxf(x4 + e4, 0.0f) + fmaxf(x5 + e5, 0.0f)
                  + fmaxf(x6 + e6, 0.0f) + fmaxf(x7 + e7, 0.0f);
        }
        for (; t < m; t++) {
            int uu = __builtin_amdgcn_readlane(u, t);
            acc0 += fmaxf(nf[((uu >> 8) << 6) + l] + sE[((uu & 255) << 6) + l], 0.0f);
        }
    }
    float epsv = 1.0f + epsp[0];
    h[(size_t)n * D + l] = fmaf(epsv, nf[(size_t)n * D + l], acc0 + acc1);
}

// ---------------------------------------------------------------------------
// BN stats, syrk-style: per-block register-accumulated partials of
// M = sum_n h_n h_n^T (64x64, 16x16 threads x 4x4 regs) and s = sum_n h_n.
// ---------------------------------------------------------------------------
__global__ __launch_bounds__(256) void k_stats(
    const float* __restrict__ h,
    float* __restrict__ pM,     // [grid][4160]: M (4096) then s (64)
    int N, int tiles)
{
    __shared__ float sH[64 * 68];   // 17408 B
    __shared__ float sred[4 * 64];
    int tid = threadIdx.x;
    int iB = tid >> 4, jB = tid & 15;
    int rg = tid >> 6, lc = tid & 63;

    float M[4][4];
    #pragma unroll
    for (int a = 0; a < 4; a++)
        #pragma unroll
        for (int b = 0; b < 4; b++) M[a][b] = 0.0f;
    float sp = 0.0f;

    for (int t = blockIdx.x; t < tiles; t += gridDim.x) {
        int row0 = t * 64;
        __syncthreads();
        {
            int r = tid >> 2, c16 = (tid & 3) * 16;
            int gr = row0 + r;
            float* dp = &sH[r * 68 + c16];
            if (gr < N) {
                const float4* hr = (const float4*)(h + (size_t)gr * D + c16);
                #pragma unroll
                for (int m2 = 0; m2 < 4; m2++) ((float4*)dp)[m2] = hr[m2];
            } else {
                #pragma unroll
                for (int m2 = 0; m2 < 16; m2++) dp[m2] = 0.0f;
            }
        }
        __syncthreads();

        #pragma unroll 8
        for (int n2 = 0; n2 < 64; n2++) {
            float4 a = *(const float4*)&sH[n2 * 68 + iB * 4];
            float4 b = *(const float4*)&sH[n2 * 68 + jB * 4];
            M[0][0] = fmaf(a.x, b.x, M[0][0]);
            M[0][1] = fmaf(a.x, b.y, M[0][1]);
            M[0][2] = fmaf(a.x, b.z, M[0][2]);
            M[0][3] = fmaf(a.x, b.w, M[0][3]);
            M[1][0] = fmaf(a.y, b.x, M[1][0]);
            M[1][1] = fmaf(a.y, b.y, M[1][1]);
            M[1][2] = fmaf(a.y, b.z, M[1][2]);
            M[1][3] = fmaf(a.y, b.w, M[1][3]);
            M[2][0] = fmaf(a.z, b.x, M[2][0]);
            M[2][1] = fmaf(a.z, b.y, M[2][1]);
            M[2][2] = fmaf(a.z, b.z, M[2][2]);
            M[2][3] = fmaf(a.z, b.w, M[2][3]);
            M[3][0] = fmaf(a.w, b.x, M[3][0]);
            M[3][1] = fmaf(a.w, b.y, M[3][1]);
            M[3][2] = fmaf(a.w, b.z, M[3][2]);
            M[3][3] = fmaf(a.w, b.w, M[3][3]);
        }
        #pragma unroll
        for (int r2 = 0; r2 < 16; r2++)
            sp += sH[(rg * 16 + r2) * 68 + lc];
    }

    float* P = pM + (size_t)blockIdx.x * 4160;
    #pragma unroll
    for (int a = 0; a < 4; a++)
        #pragma unroll
        for (int b = 0; b < 4; b++)
            P[(iB * 4 + a) * 64 + jB * 4 + b] = M[a][b];
    sred[rg * 64 + lc] = sp;
    __syncthreads();
    if (tid < 64)
        P[4096 + tid] = sred[tid] + sred[64 + tid] + sred[128 + tid] + sred[192 + tid];
}

// Reduce partials over blocks; pre-normalize by 1/N.
__global__ __launch_bounds__(256) void k_redM(
    const float* __restrict__ pM, int nblk,
    float* __restrict__ Mbar, float invN)
{
    int e = blockIdx.x * 256 + threadIdx.x;
    if (e >= 4160) return;
    float s = 0.0f;
    for (int b = 0; b < nblk; b++) s += pM[(size_t)b * 4160 + e];
    Mbar[e] = s * invN;
}

// Per-channel BN scale/shift: var_c = w^T Mbar w - (w.sbar)^2, mean = w.sbar+b1.
__global__ void k_bn(
    const float* __restrict__ Mbar,   // [4160]: M (64x64) then sbar (64)
    const float* __restrict__ W1,     // [128,64]
    const float* __restrict__ b1,
    const float* __restrict__ gamma, const float* __restrict__ beta,
    float* __restrict__ ss)
{
    __shared__ float sMb[4160];
    int tid = threadIdx.x;  // 128 threads
    for (int i = tid; i < 4160; i += 128) sMb[i] = Mbar[i];
    __syncthreads();

    int c = tid;
    float w[64];
    #pragma unroll
    for (int k = 0; k < 64; k++) w[k] = W1[c * D + k];

    float d = 0.0f;
    #pragma unroll
    for (int k = 0; k < 64; k++) d = fmaf(w[k], sMb[4096 + k], d);

    float Q = 0.0f;
    for (int k = 0; k < 64; k++) {
        float tk = 0.0f;
        #pragma unroll
        for (int j = 0; j < 64; j++) tk = fmaf(sMb[k * 64 + j], w[j], tk);
        Q = fmaf(w[k], tk, Q);
    }

    float var  = fmaxf(Q - d * d, 0.0f);
    float mean = d + b1[c];
    float sc   = gamma[c] * rsqrtf(var + 1e-5f);
    ss[c]       = sc;
    ss[128 + c] = beta[c] - mean * sc;
}

// ---------------------------------------------------------------------------
// GEMM2: persistent blocks, 32-row tiles, W1t/W2t staged once.
// LDS = 16384 + 32768 + 32768 = 81920 B exactly -> 2 blocks/CU.
// ---------------------------------------------------------------------------
__global__ __launch_bounds__(256) void k_gemm2(
    const float* __restrict__ h,
    const float* __restrict__ W1,    // [128,64]
    const float* __restrict__ b1,    // [128]
    const float* __restrict__ ss,    // scale/shift [256]
    const float* __restrict__ W2,    // [64,128]
    const float* __restrict__ b2v,   // [64]
    float* __restrict__ out,         // [N,64]
    int N, int tiles)
{
    __shared__ float AB[32 * 128];
    __shared__ float W1t[64 * 128];
    __shared__ float W2t[128 * 64];

    int tid = threadIdx.x;
    int ty = tid >> 5, tx = tid & 31;

    {   // stage W1^T: W1t[k][c]
        int c  = tid >> 1;
        int k0 = (tid & 1) * 32;
        const float4* wr = (const float4*)(W1 + c * D + k0);
        #pragma unroll
        for (int q = 0; q < 8; q++) {
            float4 u = wr[q];
            int k = k0 + q * 4;
            W1t[(k + 0) * 128 + c] = u.x;
            W1t[(k + 1) * 128 + c] = u.y;
            W1t[(k + 2) * 128 + c] = u.z;
            W1t[(k + 3) * 128 + c] = u.w;
        }
    }
    {   // stage W2^T: W2t[k][j]
        int j  = tid >> 2;
        int k0 = (tid & 3) * 32;
        const float4* wr = (const float4*)(W2 + j * D2 + k0);
        #pragma unroll
        for (int q = 0; q < 8; q++) {
            float4 u = wr[q];
            int k = k0 + q * 4;
            W2t[(k + 0) * 64 + j] = u.x;
            W2t[(k + 1) * 64 + j] = u.y;
            W2t[(k + 2) * 64 + j] = u.z;
            W2t[(k + 3) * 64 + j] = u.w;
        }
    }

    float bb0 = b1[tx * 4 + 0];
    float bb1 = b1[tx * 4 + 1];
    float bb2 = b1[tx * 4 + 2];
    float bb3 = b1[tx * 4 + 3];
    float4 scv = *(const float4*)&ss[tx * 4];
    float4 shv = *(const float4*)&ss[128 + tx * 4];
    float ob0 = b2v[tx * 2 + 0];
    float ob1 = b2v[tx * 2 + 1];

    for (int t = blockIdx.x; t < tiles; t += gridDim.x) {
        int row0 = t * 32;
        __syncthreads();
        {   // phase A: stage h tile (cols 0..63)
            int r  = tid >> 3;
            int c8 = (tid & 7) * 8;
            int gr = row0 + r;
            float* dstp = &AB[r * 128 + c8];
            if (gr < N) {
                const float4* hrow = (const float4*)(h + (size_t)gr * D + c8);
                ((float4*)dstp)[0] = hrow[0];
                ((float4*)dstp)[1] = hrow[1];
            } else {
                #pragma unroll
                for (int m = 0; m < 8; m++) dstp[m] = 0.0f;
            }
        }
        __syncthreads();

        float acc[4][4];
        #pragma unroll
        for (int i = 0; i < 4; i++)
            #pragma unroll
            for (int j = 0; j < 4; j++) acc[i][j] = 0.0f;

        #pragma unroll 4
        for (int k4 = 0; k4 < 16; k4++) {
            float4 w0 = *(const float4*)&W1t[(k4 * 4 + 0) * 128 + tx * 4];
            float4 w1 = *(const float4*)&W1t[(k4 * 4 + 1) * 128 + tx * 4];
            float4 w2 = *(const float4*)&W1t[(k4 * 4 + 2) * 128 + tx * 4];
            float4 w3 = *(const float4*)&W1t[(k4 * 4 + 3) * 128 + tx * 4];
            #pragma unroll
            for (int i = 0; i < 4; i++) {
                float4 a = *(const float4*)&AB[(ty * 4 + i) * 128 + k4 * 4];
                acc[i][0] = fmaf(a.x, w0.x, acc[i][0]);
                acc[i][1] = fmaf(a.x, w0.y, acc[i][1]);
                acc[i][2] = fmaf(a.x, w0.z, acc[i][2]);
                acc[i][3] = fmaf(a.x, w0.w, acc[i][3]);
                acc[i][0] = fmaf(a.y, w1.x, acc[i][0]);
                acc[i][1] = fmaf(a.y, w1.y, acc[i][1]);
                acc[i][2] = fmaf(a.y, w1.z, acc[i][2]);
                acc[i][3] = fmaf(a.y, w1.w, acc[i][3]);
                acc[i][0] = fmaf(a.z, w2.x, acc[i][0]);
                acc[i][1] = fmaf(a.z, w2.y, acc[i][1]);
                acc[i][2] = fmaf(a.z, w2.z, acc[i][2]);
                acc[i][3] = fmaf(a.z, w2.w, acc[i][3]);
                acc[i][0] = fmaf(a.w, w3.x, acc[i][0]);
                acc[i][1] = fmaf(a.w, w3.y, acc[i][1]);
                acc[i][2] = fmaf(a.w, w3.z, acc[i][2]);
                acc[i][3] = fmaf(a.w, w3.w, acc[i][3]);
            }
        }
        __syncthreads();

        #pragma unroll
        for (int i = 0; i < 4; i++) {
            float g0 = fmaxf(fmaf(acc[i][0] + bb0, scv.x, shv.x), 0.0f);
            float g1 = fmaxf(fmaf(acc[i][1] + bb1, scv.y, shv.y), 0.0f);
            float g2 = fmaxf(fmaf(acc[i][2] + bb2, scv.z, shv.z), 0.0f);
            float g3 = fmaxf(fmaf(acc[i][3] + bb3, scv.w, shv.w), 0.0f);
            *(float4*)&AB[(ty * 4 + i) * 128 + tx * 4] = make_float4(g0, g1, g2, g3);
        }
        __syncthreads();

        float acc2[4][2];
        #pragma unroll
        for (int i = 0; i < 4; i++) { acc2[i][0] = 0.0f; acc2[i][1] = 0.0f; }

        #pragma unroll 4
        for (int k4 = 0; k4 < 32; k4++) {
            float2 u0 = *(const float2*)&W2t[(k4 * 4 + 0) * 64 + tx * 2];
            float2 u1 = *(const float2*)&W2t[(k4 * 4 + 1) * 64 + tx * 2];
            float2 u2 = *(const float2*)&W2t[(k4 * 4 + 2) * 64 + tx * 2];
            float2 u3 = *(const float2*)&W2t[(k4 * 4 + 3) * 64 + tx * 2];
            #pragma unroll
            for (int i = 0; i < 4; i++) {
                float4 b = *(const float4*)&AB[(ty * 4 + i) * 128 + k4 * 4];
                acc2[i][0] = fmaf(b.x, u0.x, acc2[i][0]);
                acc2[i][1] = fmaf(b.x, u0.y, acc2[i][1]);
                acc2[i][0] = fmaf(b.y, u1.x, acc2[i][0]);
                acc2[i][1] = fmaf(b.y, u1.y, acc2[i][1]);
                acc2[i][0] = fmaf(b.z, u2.x, acc2[i][0]);
                acc2[i][1] = fmaf(b.z, u2.y, acc2[i][1]);
                acc2[i][0] = fmaf(b.w, u3.x, acc2[i][0]);
                acc2[i][1] = fmaf(b.w, u3.y, acc2[i][1]);
            }
        }

        #pragma unroll
        for (int i = 0; i < 4; i++) {
            int gr = row0 + ty * 4 + i;
            if (gr < N) {
                float2 pk = make_float2(acc2[i][0] + ob0, acc2[i][1] + ob1);
                ((float2*)out)[(size_t)gr * 32 + tx] = pk;
            }
        }
    }
}

// ---------------------------------------------------------------------------
extern "C" void kernel_launch(void* const* d_in, const int* in_sizes, int n_in,
                              void* d_out, int out_size, void* d_ws, size_t ws_size,
                              hipStream_t stream)
{
    const float* nf    = (const float*)d_in[0];
    const int*   ef    = (const int*)d_in[1];
    const int*   ei    = (const int*)d_in[2];
    const float* epsp  = (const float*)d_in[5];
    const float* be0   = (const float*)d_in[6];
    const float* be1   = (const float*)d_in[7];
    const float* be2   = (const float*)d_in[8];
    const float* W1    = (const float*)d_in[9];
    const float* b1    = (const float*)d_in[10];
    const float* gamma = (const float*)d_in[11];
    const float* beta  = (const float*)d_in[12];
    const float* W2    = (const float*)d_in[13];
    const float* b2v   = (const float*)d_in[14];
    float*       out   = (float*)d_out;

    int N = in_sizes[0] / D;    // 100000
    int E = in_sizes[1] / 3;    // 1600000
    int NB = (N + CHUNK - 1) / CHUNK;

    int gS = 256;                         // k_stats blocks
    int tilesS = (N + 63) / 64;           // 1563
    int tiles2 = (N + 31) / 32;           // 3125
    int g2 = 512;                         // 2 blocks/CU

    // workspace layout (4-byte elements)
    float* h       = (float*)d_ws;                    // N*64
    float* pM      = h + (size_t)N * D;               // gS*4160
    float* Mbar    = pM + (size_t)gS * 4160;          // 4160
    float* ss      = Mbar + 4160;                     // 256
    int*   cnt     = (int*)(ss + 256);                // N
    int*   offs    = cnt + N;                         // N+1
    int*   bsum    = offs + N + 1;                    // NB
    int*   boff    = bsum + NB;                       // NB
    int*   payload = boff + NB;                       // E

    hipMemsetAsync(cnt, 0, (size_t)N * sizeof(int), stream);

    int e2 = (E + 1) / 2;
    int eBlocks2 = (e2 + 255) / 256;
    k_hist<<<eBlocks2, 256, 0, stream>>>(ei, cnt, E);
    k_scan1<<<NB, 256, 0, stream>>>(cnt, offs, bsum, N);
    k_scan2<<<1, 128, 0, stream>>>(bsum, boff, NB);
    k_scan3<<<(N + 255) / 256, 256, 0, stream>>>(offs, cnt, boff, N, E);
    k_scatter<<<eBlocks2, 256, 0, stream>>>(ei, ef, cnt, payload, E);

    k_reduce<<<(N + 3) / 4, 256, 0, stream>>>(nf, offs, payload, be0, be1, be2,
                                              epsp, h, N);

    k_stats<<<gS, 256, 0, stream>>>(h, pM, N, tilesS);
    k_redM<<<(4160 + 255) / 256, 256, 0, stream>>>(pM, gS, Mbar, 1.0f / (float)N);
    k_bn<<<1, 128, 0, stream>>>(Mbar, W1, b1, gamma, beta, ss);

    k_gemm2<<<g2, 256, 0, stream>>>(h, W1, b1, ss, W2, b2v, out, N, tiles2);
}

// Round 9
// 617.051 us; speedup vs baseline: 1.0099x; 1.0099x over previous
//
#include <hip/hip_runtime.h>
#include <stdint.h>

#define D  64
#define D2 128
#define CHUNK 1024

// ---------------------------------------------------------------------------
// Histogram of dst, 2 edges/thread. cnt must be pre-zeroed.
// ---------------------------------------------------------------------------
__global__ __launch_bounds__(256) void k_hist(
    const int* __restrict__ ei, int* __restrict__ cnt, int E)
{
    int i2 = blockIdx.x * 256 + threadIdx.x;
    int e0 = i2 * 2;
    if (e0 >= E) return;
    int2 d = ((const int2*)ei)[i2];
    atomicAdd(&cnt[d.x], 1);
    if (e0 + 1 < E) atomicAdd(&cnt[d.y], 1);
}

// ---------------------------------------------------------------------------
__global__ __launch_bounds__(256) void k_scan1(
    const int* __restrict__ cnt, int* __restrict__ offs,
    int* __restrict__ bsum, int N)
{
    __shared__ int sd[256];
    int t    = threadIdx.x;
    int i0   = blockIdx.x * CHUNK + t * 4;
    int v0 = (i0 + 0 < N) ? cnt[i0 + 0] : 0;
    int v1 = (i0 + 1 < N) ? cnt[i0 + 1] : 0;
    int v2 = (i0 + 2 < N) ? cnt[i0 + 2] : 0;
    int v3 = (i0 + 3 < N) ? cnt[i0 + 3] : 0;
    int s = v0 + v1 + v2 + v3;
    sd[t] = s;
    __syncthreads();
    for (int off = 1; off < 256; off <<= 1) {
        int x = (t >= off) ? sd[t - off] : 0;
        __syncthreads();
        sd[t] += x;
        __syncthreads();
    }
    int excl = sd[t] - s;
    if (t == 255) bsum[blockIdx.x] = sd[255];
    if (i0 + 0 < N) offs[i0 + 0] = excl;
    if (i0 + 1 < N) offs[i0 + 1] = excl + v0;
    if (i0 + 2 < N) offs[i0 + 2] = excl + v0 + v1;
    if (i0 + 3 < N) offs[i0 + 3] = excl + v0 + v1 + v2;
}

__global__ void k_scan2(const int* __restrict__ bsum, int* __restrict__ boff, int NB)
{
    __shared__ int sd[128];
    int t = threadIdx.x;
    int v = (t < NB) ? bsum[t] : 0;
    sd[t] = v;
    __syncthreads();
    for (int off = 1; off < 128; off <<= 1) {
        int x = (t >= off) ? sd[t - off] : 0;
        __syncthreads();
        sd[t] += x;
        __syncthreads();
    }
    if (t < NB) boff[t] = sd[t] - v;
}

__global__ __launch_bounds__(256) void k_scan3(
    int* __restrict__ offs, int* __restrict__ cnt,
    const int* __restrict__ boff, int N, int E)
{
    int i = blockIdx.x * 256 + threadIdx.x;
    if (i < N) {
        int o = offs[i] + boff[i / CHUNK];
        offs[i] = o;
        cnt[i]  = o;
    }
    if (i == 0) offs[N] = E;
}

// ---------------------------------------------------------------------------
// Scatter, 2 edges/thread: payload[pos] = (src<<8) | code.
// ---------------------------------------------------------------------------
__global__ __launch_bounds__(256) void k_scatter(
    const int* __restrict__ ei, const int* __restrict__ ef,
    int* __restrict__ cursor, int* __restrict__ payload, int E)
{
    int i2 = blockIdx.x * 256 + threadIdx.x;
    int e0 = i2 * 2;
    if (e0 >= E) return;
    int2 d = ((const int2*)ei)[i2];
    int2 s = ((const int2*)(ei + E))[i2];
    int2 q0 = ((const int2*)ef)[3 * i2 + 0];
    int2 q1 = ((const int2*)ef)[3 * i2 + 1];
    int2 q2 = ((const int2*)ef)[3 * i2 + 2];
    int code0 = q0.x * 12 + q0.y * 2 + q1.x;
    int pos0 = atomicAdd(&cursor[d.x], 1);
    payload[pos0] = (s.x << 8) | code0;
    if (e0 + 1 < E) {
        int code1 = q1.y * 12 + q2.x * 2 + q2.y;
        int pos1 = atomicAdd(&cursor[d.y], 1);
        payload[pos1] = (s.y << 8) | code1;
    }
}

// ---------------------------------------------------------------------------
// Gather-reduce + fuse h = (1+eps)*nf + msg. One wave per node, lane=feature.
// EXACT round-6 form (measured 110 us): coalesced batch load + __shfl
// distribution + 4-way MLP unroll. (r7 scalar-load and r8 readlane variants
// both regressed: per-edge broadcast VMEM loads / VALU readlanes.)
// Embedding-sum table built in LDS.
// ---------------------------------------------------------------------------
__global__ __launch_bounds__(256) void k_reduce(
    const float* __restrict__ nf,
    const int* __restrict__ offs,
    const int* __restrict__ payload,
    const float* __restrict__ be0, const float* __restrict__ be1,
    const float* __restrict__ be2,
    const float* __restrict__ epsp,
    float* __restrict__ h, int N)
{
    __shared__ float sE[60 * D];   // 15 KB
    int tid = threadIdx.x;
    for (int i = tid; i < 60 * D; i += 256) {
        int c = i >> 6, l = i & 63;
        int f0 = c / 12, r = c % 12;
        sE[i] = be0[f0 * D + l] + be1[(r >> 1) * D + l] + be2[(r & 1) * D + l];
    }
    __syncthreads();

    int n = (blockIdx.x * 256 + tid) >> 6;
    int l = tid & 63;
    if (n >= N) return;

    int start = offs[n];
    int end   = offs[n + 1];
    float acc = 0.0f;
    for (int jb = start; jb < end; jb += 64) {
        int u = (jb + l < end) ? payload[jb + l] : 0;   // coalesced batch
        int m = end - jb; if (m > 64) m = 64;
        int t = 0;
        for (; t + 4 <= m; t += 4) {
            int a0 = __shfl(u, t + 0);
            int a1 = __shfl(u, t + 1);
            int a2 = __shfl(u, t + 2);
            int a3 = __shfl(u, t + 3);
            float x0 = nf[((a0 >> 8) << 6) + l];
            float x1 = nf[((a1 >> 8) << 6) + l];
            float x2 = nf[((a2 >> 8) << 6) + l];
            float x3 = nf[((a3 >> 8) << 6) + l];
            float e0 = sE[((a0 & 255) << 6) + l];
            float e1 = sE[((a1 & 255) << 6) + l];
            float e2 = sE[((a2 & 255) << 6) + l];
            float e3 = sE[((a3 & 255) << 6) + l];
            acc += fmaxf(x0 + e0, 0.0f) + fmaxf(x1 + e1, 0.0f)
                 + fmaxf(x2 + e2, 0.0f) + fmaxf(x3 + e3, 0.0f);
        }
        for (; t < m; t++) {
            int a = __shfl(u, t);
            acc += fmaxf(nf[((a >> 8) << 6) + l] + sE[((a & 255) << 6) + l], 0.0f);
        }
    }
    float epsv = 1.0f + epsp[0];
    h[(size_t)n * D + l] = fmaf(epsv, nf[(size_t)n * D + l], acc);
}

// ---------------------------------------------------------------------------
// BN stats, syrk-style: per-block register-accumulated partials of
// M = sum_n h_n h_n^T (64x64, 16x16 threads x 4x4 regs) and s = sum_n h_n.
// ---------------------------------------------------------------------------
__global__ __launch_bounds__(256) void k_stats(
    const float* __restrict__ h,
    float* __restrict__ pM,     // [grid][4160]: M (4096) then s (64)
    int N, int tiles)
{
    __shared__ float sH[64 * 68];   // 17408 B
    __shared__ float sred[4 * 64];
    int tid = threadIdx.x;
    int iB = tid >> 4, jB = tid & 15;
    int rg = tid >> 6, lc = tid & 63;

    float M[4][4];
    #pragma unroll
    for (int a = 0; a < 4; a++)
        #pragma unroll
        for (int b = 0; b < 4; b++) M[a][b] = 0.0f;
    float sp = 0.0f;

    for (int t = blockIdx.x; t < tiles; t += gridDim.x) {
        int row0 = t * 64;
        __syncthreads();
        {
            int r = tid >> 2, c16 = (tid & 3) * 16;
            int gr = row0 + r;
            float* dp = &sH[r * 68 + c16];
            if (gr < N) {
                const float4* hr = (const float4*)(h + (size_t)gr * D + c16);
                #pragma unroll
                for (int m2 = 0; m2 < 4; m2++) ((float4*)dp)[m2] = hr[m2];
            } else {
                #pragma unroll
                for (int m2 = 0; m2 < 16; m2++) dp[m2] = 0.0f;
            }
        }
        __syncthreads();

        #pragma unroll 8
        for (int n2 = 0; n2 < 64; n2++) {
            float4 a = *(const float4*)&sH[n2 * 68 + iB * 4];
            float4 b = *(const float4*)&sH[n2 * 68 + jB * 4];
            M[0][0] = fmaf(a.x, b.x, M[0][0]);
            M[0][1] = fmaf(a.x, b.y, M[0][1]);
            M[0][2] = fmaf(a.x, b.z, M[0][2]);
            M[0][3] = fmaf(a.x, b.w, M[0][3]);
            M[1][0] = fmaf(a.y, b.x, M[1][0]);
            M[1][1] = fmaf(a.y, b.y, M[1][1]);
            M[1][2] = fmaf(a.y, b.z, M[1][2]);
            M[1][3] = fmaf(a.y, b.w, M[1][3]);
            M[2][0] = fmaf(a.z, b.x, M[2][0]);
            M[2][1] = fmaf(a.z, b.y, M[2][1]);
            M[2][2] = fmaf(a.z, b.z, M[2][2]);
            M[2][3] = fmaf(a.z, b.w, M[2][3]);
            M[3][0] = fmaf(a.w, b.x, M[3][0]);
            M[3][1] = fmaf(a.w, b.y, M[3][1]);
            M[3][2] = fmaf(a.w, b.z, M[3][2]);
            M[3][3] = fmaf(a.w, b.w, M[3][3]);
        }
        #pragma unroll
        for (int r2 = 0; r2 < 16; r2++)
            sp += sH[(rg * 16 + r2) * 68 + lc];
    }

    float* P = pM + (size_t)blockIdx.x * 4160;
    #pragma unroll
    for (int a = 0; a < 4; a++)
        #pragma unroll
        for (int b = 0; b < 4; b++)
            P[(iB * 4 + a) * 64 + jB * 4 + b] = M[a][b];
    sred[rg * 64 + lc] = sp;
    __syncthreads();
    if (tid < 64)
        P[4096 + tid] = sred[tid] + sred[64 + tid] + sred[128 + tid] + sred[192 + tid];
}

// Reduce partials over blocks; pre-normalize by 1/N.
__global__ __launch_bounds__(256) void k_redM(
    const float* __restrict__ pM, int nblk,
    float* __restrict__ Mbar, float invN)
{
    int e = blockIdx.x * 256 + threadIdx.x;
    if (e >= 4160) return;
    float s = 0.0f;
    for (int b = 0; b < nblk; b++) s += pM[(size_t)b * 4160 + e];
    Mbar[e] = s * invN;
}

// Per-channel BN scale/shift: var_c = w^T Mbar w - (w.sbar)^2, mean = w.sbar+b1.
__global__ void k_bn(
    const float* __restrict__ Mbar,   // [4160]: M (64x64) then sbar (64)
    const float* __restrict__ W1,     // [128,64]
    const float* __restrict__ b1,
    const float* __restrict__ gamma, const float* __restrict__ beta,
    float* __restrict__ ss)
{
    __shared__ float sMb[4160];
    int tid = threadIdx.x;  // 128 threads
    for (int i = tid; i < 4160; i += 128) sMb[i] = Mbar[i];
    __syncthreads();

    int c = tid;
    float w[64];
    #pragma unroll
    for (int k = 0; k < 64; k++) w[k] = W1[c * D + k];

    float d = 0.0f;
    #pragma unroll
    for (int k = 0; k < 64; k++) d = fmaf(w[k], sMb[4096 + k], d);

    float Q = 0.0f;
    for (int k = 0; k < 64; k++) {
        float tk = 0.0f;
        #pragma unroll
        for (int j = 0; j < 64; j++) tk = fmaf(sMb[k * 64 + j], w[j], tk);
        Q = fmaf(w[k], tk, Q);
    }

    float var  = fmaxf(Q - d * d, 0.0f);
    float mean = d + b1[c];
    float sc   = gamma[c] * rsqrtf(var + 1e-5f);
    ss[c]       = sc;
    ss[128 + c] = beta[c] - mean * sc;
}

// ---------------------------------------------------------------------------
// GEMM2: persistent blocks, 64-row tiles (amortize W-tile LDS reads over 2x
// rows vs r8's 32-row tiles; fma:LDS-byte ratio 2.0 -> 2.7).
// LDS = 32768*3 = 98304 B -> 1 block/CU (LDS-throughput bound, not latency).
// Stage1: thread (ty=tid>>5, tx=tid&31): rows ty*8..+7, cols tx*4..+3.
// Stage2: rows ty*8..+7, cols tx*2..+1.
// ---------------------------------------------------------------------------
__global__ __launch_bounds__(256) void k_gemm2(
    const float* __restrict__ h,
    const float* __restrict__ W1,    // [128,64]
    const float* __restrict__ b1,    // [128]
    const float* __restrict__ ss,    // scale/shift [256]
    const float* __restrict__ W2,    // [64,128]
    const float* __restrict__ b2v,   // [64]
    float* __restrict__ out,         // [N,64]
    int N, int tiles)
{
    __shared__ float AB[64 * 128];    // 32768 B: phase A cols 0..63, phase B 0..127
    __shared__ float W1t[64 * 128];   // 32768 B
    __shared__ float W2t[128 * 64];   // 32768 B

    int tid = threadIdx.x;
    int ty = tid >> 5, tx = tid & 31;

    {   // stage W1^T: W1t[k][c]
        int c  = tid >> 1;
        int k0 = (tid & 1) * 32;
        const float4* wr = (const float4*)(W1 + c * D + k0);
        #pragma unroll
        for (int q = 0; q < 8; q++) {
            float4 u = wr[q];
            int k = k0 + q * 4;
            W1t[(k + 0) * 128 + c] = u.x;
            W1t[(k + 1) * 128 + c] = u.y;
            W1t[(k + 2) * 128 + c] = u.z;
            W1t[(k + 3) * 128 + c] = u.w;
        }
    }
    {   // stage W2^T: W2t[k][j]
        int j  = tid >> 2;
        int k0 = (tid & 3) * 32;
        const float4* wr = (const float4*)(W2 + j * D2 + k0);
        #pragma unroll
        for (int q = 0; q < 8; q++) {
            float4 u = wr[q];
            int k = k0 + q * 4;
            W2t[(k + 0) * 64 + j] = u.x;
            W2t[(k + 1) * 64 + j] = u.y;
            W2t[(k + 2) * 64 + j] = u.z;
            W2t[(k + 3) * 64 + j] = u.w;
        }
    }

    float bb0 = b1[tx * 4 + 0];
    float bb1 = b1[tx * 4 + 1];
    float bb2 = b1[tx * 4 + 2];
    float bb3 = b1[tx * 4 + 3];
    float4 scv = *(const float4*)&ss[tx * 4];
    float4 shv = *(const float4*)&ss[128 + tx * 4];
    float ob0 = b2v[tx * 2 + 0];
    float ob1 = b2v[tx * 2 + 1];

    for (int t = blockIdx.x; t < tiles; t += gridDim.x) {
        int row0 = t * 64;
        __syncthreads();   // protect AB from previous stage-2 reads (& W staging, iter 0)
        {   // phase A: stage h tile, 64 rows x 64 cols
            int r   = tid >> 2;
            int c16 = (tid & 3) * 16;
            int gr  = row0 + r;
            float* dstp = &AB[r * 128 + c16];
            if (gr < N) {
                const float4* hrow = (const float4*)(h + (size_t)gr * D + c16);
                #pragma unroll
                for (int m = 0; m < 4; m++) ((float4*)dstp)[m] = hrow[m];
            } else {
                #pragma unroll
                for (int m = 0; m < 16; m++) dstp[m] = 0.0f;
            }
        }
        __syncthreads();

        float acc[8][4];
        #pragma unroll
        for (int i = 0; i < 8; i++)
            #pragma unroll
            for (int j = 0; j < 4; j++) acc[i][j] = 0.0f;

        #pragma unroll 4
        for (int k4 = 0; k4 < 16; k4++) {
            float4 w0 = *(const float4*)&W1t[(k4 * 4 + 0) * 128 + tx * 4];
            float4 w1 = *(const float4*)&W1t[(k4 * 4 + 1) * 128 + tx * 4];
            float4 w2 = *(const float4*)&W1t[(k4 * 4 + 2) * 128 + tx * 4];
            float4 w3 = *(const float4*)&W1t[(k4 * 4 + 3) * 128 + tx * 4];
            #pragma unroll
            for (int i = 0; i < 8; i++) {
                float4 a = *(const float4*)&AB[(ty * 8 + i) * 128 + k4 * 4];
                acc[i][0] = fmaf(a.x, w0.x, acc[i][0]);
                acc[i][1] = fmaf(a.x, w0.y, acc[i][1]);
                acc[i][2] = fmaf(a.x, w0.z, acc[i][2]);
                acc[i][3] = fmaf(a.x, w0.w, acc[i][3]);
                acc[i][0] = fmaf(a.y, w1.x, acc[i][0]);
                acc[i][1] = fmaf(a.y, w1.y, acc[i][1]);
                acc[i][2] = fmaf(a.y, w1.z, acc[i][2]);
                acc[i][3] = fmaf(a.y, w1.w, acc[i][3]);
                acc[i][0] = fmaf(a.z, w2.x, acc[i][0]);
                acc[i][1] = fmaf(a.z, w2.y, acc[i][1]);
                acc[i][2] = fmaf(a.z, w2.z, acc[i][2]);
                acc[i][3] = fmaf(a.z, w2.w, acc[i][3]);
                acc[i][0] = fmaf(a.w, w3.x, acc[i][0]);
                acc[i][1] = fmaf(a.w, w3.y, acc[i][1]);
                acc[i][2] = fmaf(a.w, w3.z, acc[i][2]);
                acc[i][3] = fmaf(a.w, w3.w, acc[i][3]);
            }
        }
        __syncthreads();   // all stage-1 reads of AB done

        #pragma unroll
        for (int i = 0; i < 8; i++) {
            float g0 = fmaxf(fmaf(acc[i][0] + bb0, scv.x, shv.x), 0.0f);
            float g1 = fmaxf(fmaf(acc[i][1] + bb1, scv.y, shv.y), 0.0f);
            float g2 = fmaxf(fmaf(acc[i][2] + bb2, scv.z, shv.z), 0.0f);
            float g3 = fmaxf(fmaf(acc[i][3] + bb3, scv.w, shv.w), 0.0f);
            *(float4*)&AB[(ty * 8 + i) * 128 + tx * 4] = make_float4(g0, g1, g2, g3);
        }
        __syncthreads();   // B visible

        float acc2[8][2];
        #pragma unroll
        for (int i = 0; i < 8; i++) { acc2[i][0] = 0.0f; acc2[i][1] = 0.0f; }

        #pragma unroll 4
        for (int k4 = 0; k4 < 32; k4++) {
            float2 u0 = *(const float2*)&W2t[(k4 * 4 + 0) * 64 + tx * 2];
            float2 u1 = *(const float2*)&W2t[(k4 * 4 + 1) * 64 + tx * 2];
            float2 u2 = *(const float2*)&W2t[(k4 * 4 + 2) * 64 + tx * 2];
            float2 u3 = *(const float2*)&W2t[(k4 * 4 + 3) * 64 + tx * 2];
            #pragma unroll
            for (int i = 0; i < 8; i++) {
                float4 b = *(const float4*)&AB[(ty * 8 + i) * 128 + k4 * 4];
                acc2[i][0] = fmaf(b.x, u0.x, acc2[i][0]);
                acc2[i][1] = fmaf(b.x, u0.y, acc2[i][1]);
                acc2[i][0] = fmaf(b.y, u1.x, acc2[i][0]);
                acc2[i][1] = fmaf(b.y, u1.y, acc2[i][1]);
                acc2[i][0] = fmaf(b.z, u2.x, acc2[i][0]);
                acc2[i][1] = fmaf(b.z, u2.y, acc2[i][1]);
                acc2[i][0] = fmaf(b.w, u3.x, acc2[i][0]);
                acc2[i][1] = fmaf(b.w, u3.y, acc2[i][1]);
            }
        }

        #pragma unroll
        for (int i = 0; i < 8; i++) {
            int gr = row0 + ty * 8 + i;
            if (gr < N) {
                float2 pk = make_float2(acc2[i][0] + ob0, acc2[i][1] + ob1);
                ((float2*)out)[(size_t)gr * 32 + tx] = pk;
            }
        }
    }
}

// ---------------------------------------------------------------------------
extern "C" void kernel_launch(void* const* d_in, const int* in_sizes, int n_in,
                              void* d_out, int out_size, void* d_ws, size_t ws_size,
                              hipStream_t stream)
{
    const float* nf    = (const float*)d_in[0];
    const int*   ef    = (const int*)d_in[1];
    const int*   ei    = (const int*)d_in[2];
    const float* epsp  = (const float*)d_in[5];
    const float* be0   = (const float*)d_in[6];
    const float* be1   = (const float*)d_in[7];
    const float* be2   = (const float*)d_in[8];
    const float* W1    = (const float*)d_in[9];
    const float* b1    = (const float*)d_in[10];
    const float* gamma = (const float*)d_in[11];
    const float* beta  = (const float*)d_in[12];
    const float* W2    = (const float*)d_in[13];
    const float* b2v   = (const float*)d_in[14];
    float*       out   = (float*)d_out;

    int N = in_sizes[0] / D;    // 100000
    int E = in_sizes[1] / 3;    // 1600000
    int NB = (N + CHUNK - 1) / CHUNK;

    int gS = 128;                         // k_stats blocks
    int tilesS = (N + 63) / 64;           // 1563
    int tiles2 = (N + 63) / 64;           // 1563 (64-row tiles)
    int g2 = 256;                         // 1 block/CU (96 KB LDS)

    // workspace layout (4-byte elements)
    float* h       = (float*)d_ws;                    // N*64
    float* pM      = h + (size_t)N * D;               // gS*4160
    float* Mbar    = pM + (size_t)gS * 4160;          // 4160
    float* ss      = Mbar + 4160;                     // 256
    int*   cnt     = (int*)(ss + 256);                // N
    int*   offs    = cnt + N;                         // N+1
    int*   bsum    = offs + N + 1;                    // NB
    int*   boff    = bsum + NB;                       // NB
    int*   payload = boff + NB;                       // E

    hipMemsetAsync(cnt, 0, (size_t)N * sizeof(int), stream);

    int e2 = (E + 1) / 2;
    int eBlocks2 = (e2 + 255) / 256;
    k_hist<<<eBlocks2, 256, 0, stream>>>(ei, cnt, E);
    k_scan1<<<NB, 256, 0, stream>>>(cnt, offs, bsum, N);
    k_scan2<<<1, 128, 0, stream>>>(bsum, boff, NB);
    k_scan3<<<(N + 255) / 256, 256, 0, stream>>>(offs, cnt, boff, N, E);
    k_scatter<<<eBlocks2, 256, 0, stream>>>(ei, ef, cnt, payload, E);

    k_reduce<<<(N + 3) / 4, 256, 0, stream>>>(nf, offs, payload, be0, be1, be2,
                                              epsp, h, N);

    k_stats<<<gS, 256, 0, stream>>>(h, pM, N, tilesS);
    k_redM<<<(4160 + 255) / 256, 256, 0, stream>>>(pM, gS, Mbar, 1.0f / (float)N);
    k_bn<<<1, 128, 0, stream>>>(Mbar, W1, b1, gamma, beta, ss);

    k_gemm2<<<g2, 256, 0, stream>>>(h, W1, b1, ss, W2, b2v, out, N, tiles2);
}

// Round 10
// 593.620 us; speedup vs baseline: 1.0498x; 1.0395x over previous
//
#include <hip/hip_runtime.h>
#include <stdint.h>

#define D  64
#define D2 128
#define CHUNK 1024

// ---------------------------------------------------------------------------
// Embedding-sum table: embsum[code][0:64], code = f0*12 + f1*2 + f2 (60 codes)
// ---------------------------------------------------------------------------
__global__ void k_embsum(
    const float* __restrict__ be0, const float* __restrict__ be1,
    const float* __restrict__ be2, float* __restrict__ embsum)
{
    int c = blockIdx.x;      // 0..59
    int t = threadIdx.x;     // 0..63
    int f0 = c / 12;
    int r  = c % 12;
    int f1 = r / 2;
    int f2 = r % 2;
    embsum[c * D + t] = be0[f0 * D + t] + be1[f1 * D + t] + be2[f2 * D + t];
}

// ---------------------------------------------------------------------------
// Histogram of dst, 2 edges/thread. cnt must be pre-zeroed.
// ---------------------------------------------------------------------------
__global__ __launch_bounds__(256) void k_hist(
    const int* __restrict__ ei, int* __restrict__ cnt, int E)
{
    int i2 = blockIdx.x * 256 + threadIdx.x;
    int e0 = i2 * 2;
    if (e0 >= E) return;
    int2 d = ((const int2*)ei)[i2];
    atomicAdd(&cnt[d.x], 1);
    if (e0 + 1 < E) atomicAdd(&cnt[d.y], 1);
}

// ---------------------------------------------------------------------------
__global__ __launch_bounds__(256) void k_scan1(
    const int* __restrict__ cnt, int* __restrict__ offs,
    int* __restrict__ bsum, int N)
{
    __shared__ int sd[256];
    int t    = threadIdx.x;
    int i0   = blockIdx.x * CHUNK + t * 4;
    int v0 = (i0 + 0 < N) ? cnt[i0 + 0] : 0;
    int v1 = (i0 + 1 < N) ? cnt[i0 + 1] : 0;
    int v2 = (i0 + 2 < N) ? cnt[i0 + 2] : 0;
    int v3 = (i0 + 3 < N) ? cnt[i0 + 3] : 0;
    int s = v0 + v1 + v2 + v3;
    sd[t] = s;
    __syncthreads();
    for (int off = 1; off < 256; off <<= 1) {
        int x = (t >= off) ? sd[t - off] : 0;
        __syncthreads();
        sd[t] += x;
        __syncthreads();
    }
    int excl = sd[t] - s;
    if (t == 255) bsum[blockIdx.x] = sd[255];
    if (i0 + 0 < N) offs[i0 + 0] = excl;
    if (i0 + 1 < N) offs[i0 + 1] = excl + v0;
    if (i0 + 2 < N) offs[i0 + 2] = excl + v0 + v1;
    if (i0 + 3 < N) offs[i0 + 3] = excl + v0 + v1 + v2;
}

__global__ void k_scan2(const int* __restrict__ bsum, int* __restrict__ boff, int NB)
{
    __shared__ int sd[128];
    int t = threadIdx.x;
    int v = (t < NB) ? bsum[t] : 0;
    sd[t] = v;
    __syncthreads();
    for (int off = 1; off < 128; off <<= 1) {
        int x = (t >= off) ? sd[t - off] : 0;
        __syncthreads();
        sd[t] += x;
        __syncthreads();
    }
    if (t < NB) boff[t] = sd[t] - v;
}

__global__ __launch_bounds__(256) void k_scan3(
    int* __restrict__ offs, int* __restrict__ cnt,
    const int* __restrict__ boff, int N, int E)
{
    int i = blockIdx.x * 256 + threadIdx.x;
    if (i < N) {
        int o = offs[i] + boff[i / CHUNK];
        offs[i] = o;
        cnt[i]  = o;
    }
    if (i == 0) offs[N] = E;
}

// ---------------------------------------------------------------------------
// Scatter, 2 edges/thread: payload[pos] = src | (code<<17)  (r6 packing).
// ---------------------------------------------------------------------------
__global__ __launch_bounds__(256) void k_scatter(
    const int* __restrict__ ei, const int* __restrict__ ef,
    int* __restrict__ cursor, int* __restrict__ payload, int E)
{
    int i2 = blockIdx.x * 256 + threadIdx.x;
    int e0 = i2 * 2;
    if (e0 >= E) return;
    int2 d = ((const int2*)ei)[i2];
    int2 s = ((const int2*)(ei + E))[i2];
    int2 q0 = ((const int2*)ef)[3 * i2 + 0];
    int2 q1 = ((const int2*)ef)[3 * i2 + 1];
    int2 q2 = ((const int2*)ef)[3 * i2 + 2];
    int code0 = q0.x * 12 + q0.y * 2 + q1.x;
    int pos0 = atomicAdd(&cursor[d.x], 1);
    payload[pos0] = s.x | (code0 << 17);
    if (e0 + 1 < E) {
        int code1 = q1.y * 12 + q2.x * 2 + q2.y;
        int pos1 = atomicAdd(&cursor[d.y], 1);
        payload[pos1] = s.y | (code1 << 17);
    }
}

// ---------------------------------------------------------------------------
// Gather-reduce + fuse h = (1+eps)*nf + msg. One wave per node, lane=feature.
// BYTE-FOR-BYTE the r6 form measured at 110 us (VALUBusy 38%, VGPR 12):
// precomputed global embsum (simple copy prologue), src|(code<<17) packing,
// coalesced batch load + __shfl distribution + 4-way unroll.
// Node range [n0,n1) so the work can be split into 2 dispatches (profiling
// visibility: top-5 table lists dispatches, and one monolithic k_reduce
// masks every other kernel).
// ---------------------------------------------------------------------------
__global__ __launch_bounds__(256) void k_reduce(
    const float* __restrict__ nf,
    const int* __restrict__ offs,
    const int* __restrict__ payload,
    const float* __restrict__ embsum,
    const float* __restrict__ epsp,
    float* __restrict__ h, int n0, int n1)
{
    __shared__ float sE[60 * D];   // 15 KB
    int tid = threadIdx.x;
    for (int i = tid; i < 60 * D; i += 256) sE[i] = embsum[i];
    __syncthreads();

    int n = n0 + ((blockIdx.x * 256 + tid) >> 6);
    int l = tid & 63;
    if (n >= n1) return;

    int start = offs[n];
    int end   = offs[n + 1];
    float acc = 0.0f;
    for (int jb = start; jb < end; jb += 64) {
        int u = (jb + l < end) ? payload[jb + l] : 0;   // coalesced batch
        int m = end - jb; if (m > 64) m = 64;
        int t = 0;
        for (; t + 4 <= m; t += 4) {
            int a0 = __shfl(u, t + 0);
            int a1 = __shfl(u, t + 1);
            int a2 = __shfl(u, t + 2);
            int a3 = __shfl(u, t + 3);
            float x0 = nf[(size_t)(a0 & 0x1FFFF) * D + l];
            float x1 = nf[(size_t)(a1 & 0x1FFFF) * D + l];
            float x2 = nf[(size_t)(a2 & 0x1FFFF) * D + l];
            float x3 = nf[(size_t)(a3 & 0x1FFFF) * D + l];
            float e0 = sE[(a0 >> 17) * D + l];
            float e1 = sE[(a1 >> 17) * D + l];
            float e2 = sE[(a2 >> 17) * D + l];
            float e3 = sE[(a3 >> 17) * D + l];
            acc += fmaxf(x0 + e0, 0.0f) + fmaxf(x1 + e1, 0.0f)
                 + fmaxf(x2 + e2, 0.0f) + fmaxf(x3 + e3, 0.0f);
        }
        for (; t < m; t++) {
            int a = __shfl(u, t);
            acc += fmaxf(nf[(size_t)(a & 0x1FFFF) * D + l] + sE[(a >> 17) * D + l], 0.0f);
        }
    }
    float epsv = 1.0f + epsp[0];
    h[(size_t)n * D + l] = fmaf(epsv, nf[(size_t)n * D + l], acc);
}

// ---------------------------------------------------------------------------
// BN stats, syrk-style: per-block register-accumulated partials of
// M = sum_n h_n h_n^T (64x64, 16x16 threads x 4x4 regs) and s = sum_n h_n.
// ---------------------------------------------------------------------------
__global__ __launch_bounds__(256) void k_stats(
    const float* __restrict__ h,
    float* __restrict__ pM,     // [grid][4160]: M (4096) then s (64)
    int N, int tiles)
{
    __shared__ float sH[64 * 68];   // 17408 B
    __shared__ float sred[4 * 64];
    int tid = threadIdx.x;
    int iB = tid >> 4, jB = tid & 15;
    int rg = tid >> 6, lc = tid & 63;

    float M[4][4];
    #pragma unroll
    for (int a = 0; a < 4; a++)
        #pragma unroll
        for (int b = 0; b < 4; b++) M[a][b] = 0.0f;
    float sp = 0.0f;

    for (int t = blockIdx.x; t < tiles; t += gridDim.x) {
        int row0 = t * 64;
        __syncthreads();
        {
            int r = tid >> 2, c16 = (tid & 3) * 16;
            int gr = row0 + r;
            float* dp = &sH[r * 68 + c16];
            if (gr < N) {
                const float4* hr = (const float4*)(h + (size_t)gr * D + c16);
                #pragma unroll
                for (int m2 = 0; m2 < 4; m2++) ((float4*)dp)[m2] = hr[m2];
            } else {
                #pragma unroll
                for (int m2 = 0; m2 < 16; m2++) dp[m2] = 0.0f;
            }
        }
        __syncthreads();

        #pragma unroll 8
        for (int n2 = 0; n2 < 64; n2++) {
            float4 a = *(const float4*)&sH[n2 * 68 + iB * 4];
            float4 b = *(const float4*)&sH[n2 * 68 + jB * 4];
            M[0][0] = fmaf(a.x, b.x, M[0][0]);
            M[0][1] = fmaf(a.x, b.y, M[0][1]);
            M[0][2] = fmaf(a.x, b.z, M[0][2]);
            M[0][3] = fmaf(a.x, b.w, M[0][3]);
            M[1][0] = fmaf(a.y, b.x, M[1][0]);
            M[1][1] = fmaf(a.y, b.y, M[1][1]);
            M[1][2] = fmaf(a.y, b.z, M[1][2]);
            M[1][3] = fmaf(a.y, b.w, M[1][3]);
            M[2][0] = fmaf(a.z, b.x, M[2][0]);
            M[2][1] = fmaf(a.z, b.y, M[2][1]);
            M[2][2] = fmaf(a.z, b.z, M[2][2]);
            M[2][3] = fmaf(a.z, b.w, M[2][3]);
            M[3][0] = fmaf(a.w, b.x, M[3][0]);
            M[3][1] = fmaf(a.w, b.y, M[3][1]);
            M[3][2] = fmaf(a.w, b.z, M[3][2]);
            M[3][3] = fmaf(a.w, b.w, M[3][3]);
        }
        #pragma unroll
        for (int r2 = 0; r2 < 16; r2++)
            sp += sH[(rg * 16 + r2) * 68 + lc];
    }

    float* P = pM + (size_t)blockIdx.x * 4160;
    #pragma unroll
    for (int a = 0; a < 4; a++)
        #pragma unroll
        for (int b = 0; b < 4; b++)
            P[(iB * 4 + a) * 64 + jB * 4 + b] = M[a][b];
    sred[rg * 64 + lc] = sp;
    __syncthreads();
    if (tid < 64)
        P[4096 + tid] = sred[tid] + sred[64 + tid] + sred[128 + tid] + sred[192 + tid];
}

// Reduce partials over blocks; pre-normalize by 1/N.
__global__ __launch_bounds__(256) void k_redM(
    const float* __restrict__ pM, int nblk,
    float* __restrict__ Mbar, float invN)
{
    int e = blockIdx.x * 256 + threadIdx.x;
    if (e >= 4160) return;
    float s = 0.0f;
    for (int b = 0; b < nblk; b++) s += pM[(size_t)b * 4160 + e];
    Mbar[e] = s * invN;
}

// Per-channel BN scale/shift: var_c = w^T Mbar w - (w.sbar)^2, mean = w.sbar+b1.
__global__ void k_bn(
    const float* __restrict__ Mbar,   // [4160]: M (64x64) then sbar (64)
    const float* __restrict__ W1,     // [128,64]
    const float* __restrict__ b1,
    const float* __restrict__ gamma, const float* __restrict__ beta,
    float* __restrict__ ss)
{
    __shared__ float sMb[4160];
    int tid = threadIdx.x;  // 128 threads
    for (int i = tid; i < 4160; i += 128) sMb[i] = Mbar[i];
    __syncthreads();

    int c = tid;
    float w[64];
    #pragma unroll
    for (int k = 0; k < 64; k++) w[k] = W1[c * D + k];

    float d = 0.0f;
    #pragma unroll
    for (int k = 0; k < 64; k++) d = fmaf(w[k], sMb[4096 + k], d);

    float Q = 0.0f;
    for (int k = 0; k < 64; k++) {
        float tk = 0.0f;
        #pragma unroll
        for (int j = 0; j < 64; j++) tk = fmaf(sMb[k * 64 + j], w[j], tk);
        Q = fmaf(w[k], tk, Q);
    }

    float var  = fmaxf(Q - d * d, 0.0f);
    float mean = d + b1[c];
    float sc   = gamma[c] * rsqrtf(var + 1e-5f);
    ss[c]       = sc;
    ss[128 + c] = beta[c] - mean * sc;
}

// ---------------------------------------------------------------------------
// GEMM2: persistent blocks, 64-row tiles, W1t/W2t staged once.
// LDS = 32768*3 = 98304 B -> 1 block/CU.
// ---------------------------------------------------------------------------
__global__ __launch_bounds__(256) void k_gemm2(
    const float* __restrict__ h,
    const float* __restrict__ W1,    // [128,64]
    const float* __restrict__ b1,    // [128]
    const float* __restrict__ ss,    // scale/shift [256]
    const float* __restrict__ W2,    // [64,128]
    const float* __restrict__ b2v,   // [64]
    float* __restrict__ out,         // [N,64]
    int N, int tiles)
{
    __shared__ float AB[64 * 128];
    __shared__ float W1t[64 * 128];
    __shared__ float W2t[128 * 64];

    int tid = threadIdx.x;
    int ty = tid >> 5, tx = tid & 31;

    {   // stage W1^T: W1t[k][c]
        int c  = tid >> 1;
        int k0 = (tid & 1) * 32;
        const float4* wr = (const float4*)(W1 + c * D + k0);
        #pragma unroll
        for (int q = 0; q < 8; q++) {
            float4 u = wr[q];
            int k = k0 + q * 4;
            W1t[(k + 0) * 128 + c] = u.x;
            W1t[(k + 1) * 128 + c] = u.y;
            W1t[(k + 2) * 128 + c] = u.z;
            W1t[(k + 3) * 128 + c] = u.w;
        }
    }
    {   // stage W2^T: W2t[k][j]
        int j  = tid >> 2;
        int k0 = (tid & 3) * 32;
        const float4* wr = (const float4*)(W2 + j * D2 + k0);
        #pragma unroll
        for (int q = 0; q < 8; q++) {
            float4 u = wr[q];
            int k = k0 + q * 4;
            W2t[(k + 0) * 64 + j] = u.x;
            W2t[(k + 1) * 64 + j] = u.y;
            W2t[(k + 2) * 64 + j] = u.z;
            W2t[(k + 3) * 64 + j] = u.w;
        }
    }

    float bb0 = b1[tx * 4 + 0];
    float bb1 = b1[tx * 4 + 1];
    float bb2 = b1[tx * 4 + 2];
    float bb3 = b1[tx * 4 + 3];
    float4 scv = *(const float4*)&ss[tx * 4];
    float4 shv = *(const float4*)&ss[128 + tx * 4];
    float ob0 = b2v[tx * 2 + 0];
    float ob1 = b2v[tx * 2 + 1];

    for (int t = blockIdx.x; t < tiles; t += gridDim.x) {
        int row0 = t * 64;
        __syncthreads();
        {   // phase A: stage h tile, 64 rows x 64 cols
            int r   = tid >> 2;
            int c16 = (tid & 3) * 16;
            int gr  = row0 + r;
            float* dstp = &AB[r * 128 + c16];
            if (gr < N) {
                const float4* hrow = (const float4*)(h + (size_t)gr * D + c16);
                #pragma unroll
                for (int m = 0; m < 4; m++) ((float4*)dstp)[m] = hrow[m];
            } else {
                #pragma unroll
                for (int m = 0; m < 16; m++) dstp[m] = 0.0f;
            }
        }
        __syncthreads();

        float acc[8][4];
        #pragma unroll
        for (int i = 0; i < 8; i++)
            #pragma unroll
            for (int j = 0; j < 4; j++) acc[i][j] = 0.0f;

        #pragma unroll 4
        for (int k4 = 0; k4 < 16; k4++) {
            float4 w0 = *(const float4*)&W1t[(k4 * 4 + 0) * 128 + tx * 4];
            float4 w1 = *(const float4*)&W1t[(k4 * 4 + 1) * 128 + tx * 4];
            float4 w2 = *(const float4*)&W1t[(k4 * 4 + 2) * 128 + tx * 4];
            float4 w3 = *(const float4*)&W1t[(k4 * 4 + 3) * 128 + tx * 4];
            #pragma unroll
            for (int i = 0; i < 8; i++) {
                float4 a = *(const float4*)&AB[(ty * 8 + i) * 128 + k4 * 4];
                acc[i][0] = fmaf(a.x, w0.x, acc[i][0]);
                acc[i][1] = fmaf(a.x, w0.y, acc[i][1]);
                acc[i][2] = fmaf(a.x, w0.z, acc[i][2]);
                acc[i][3] = fmaf(a.x, w0.w, acc[i][3]);
                acc[i][0] = fmaf(a.y, w1.x, acc[i][0]);
                acc[i][1] = fmaf(a.y, w1.y, acc[i][1]);
                acc[i][2] = fmaf(a.y, w1.z, acc[i][2]);
                acc[i][3] = fmaf(a.y, w1.w, acc[i][3]);
                acc[i][0] = fmaf(a.z, w2.x, acc[i][0]);
                acc[i][1] = fmaf(a.z, w2.y, acc[i][1]);
                acc[i][2] = fmaf(a.z, w2.z, acc[i][2]);
                acc[i][3] = fmaf(a.z, w2.w, acc[i][3]);
                acc[i][0] = fmaf(a.w, w3.x, acc[i][0]);
                acc[i][1] = fmaf(a.w, w3.y, acc[i][1]);
                acc[i][2] = fmaf(a.w, w3.z, acc[i][2]);
                acc[i][3] = fmaf(a.w, w3.w, acc[i][3]);
            }
        }
        __syncthreads();

        #pragma unroll
        for (int i = 0; i < 8; i++) {
            float g0 = fmaxf(fmaf(acc[i][0] + bb0, scv.x, shv.x), 0.0f);
            float g1 = fmaxf(fmaf(acc[i][1] + bb1, scv.y, shv.y), 0.0f);
            float g2 = fmaxf(fmaf(acc[i][2] + bb2, scv.z, shv.z), 0.0f);
            float g3 = fmaxf(fmaf(acc[i][3] + bb3, scv.w, shv.w), 0.0f);
            *(float4*)&AB[(ty * 8 + i) * 128 + tx * 4] = make_float4(g0, g1, g2, g3);
        }
        __syncthreads();

        float acc2[8][2];
        #pragma unroll
        for (int i = 0; i < 8; i++) { acc2[i][0] = 0.0f; acc2[i][1] = 0.0f; }

        #pragma unroll 4
        for (int k4 = 0; k4 < 32; k4++) {
            float2 u0 = *(const float2*)&W2t[(k4 * 4 + 0) * 64 + tx * 2];
            float2 u1 = *(const float2*)&W2t[(k4 * 4 + 1) * 64 + tx * 2];
            float2 u2 = *(const float2*)&W2t[(k4 * 4 + 2) * 64 + tx * 2];
            float2 u3 = *(const float2*)&W2t[(k4 * 4 + 3) * 64 + tx * 2];
            #pragma unroll
            for (int i = 0; i < 8; i++) {
                float4 b = *(const float4*)&AB[(ty * 8 + i) * 128 + k4 * 4];
                acc2[i][0] = fmaf(b.x, u0.x, acc2[i][0]);
                acc2[i][1] = fmaf(b.x, u0.y, acc2[i][1]);
                acc2[i][0] = fmaf(b.y, u1.x, acc2[i][0]);
                acc2[i][1] = fmaf(b.y, u1.y, acc2[i][1]);
                acc2[i][0] = fmaf(b.z, u2.x, acc2[i][0]);
                acc2[i][1] = fmaf(b.z, u2.y, acc2[i][1]);
                acc2[i][0] = fmaf(b.w, u3.x, acc2[i][0]);
                acc2[i][1] = fmaf(b.w, u3.y, acc2[i][1]);
            }
        }

        #pragma unroll
        for (int i = 0; i < 8; i++) {
            int gr = row0 + ty * 8 + i;
            if (gr < N) {
                float2 pk = make_float2(acc2[i][0] + ob0, acc2[i][1] + ob1);
                ((float2*)out)[(size_t)gr * 32 + tx] = pk;
            }
        }
    }
}

// ---------------------------------------------------------------------------
extern "C" void kernel_launch(void* const* d_in, const int* in_sizes, int n_in,
                              void* d_out, int out_size, void* d_ws, size_t ws_size,
                              hipStream_t stream)
{
    const float* nf    = (const float*)d_in[0];
    const int*   ef    = (const int*)d_in[1];
    const int*   ei    = (const int*)d_in[2];
    const float* epsp  = (const float*)d_in[5];
    const float* be0   = (const float*)d_in[6];
    const float* be1   = (const float*)d_in[7];
    const float* be2   = (const float*)d_in[8];
    const float* W1    = (const float*)d_in[9];
    const float* b1    = (const float*)d_in[10];
    const float* gamma = (const float*)d_in[11];
    const float* beta  = (const float*)d_in[12];
    const float* W2    = (const float*)d_in[13];
    const float* b2v   = (const float*)d_in[14];
    float*       out   = (float*)d_out;

    int N = in_sizes[0] / D;    // 100000
    int E = in_sizes[1] / 3;    // 1600000
    int NB = (N + CHUNK - 1) / CHUNK;

    int gS = 128;                         // k_stats blocks
    int tilesS = (N + 63) / 64;           // 1563
    int tiles2 = (N + 63) / 64;           // 1563 (64-row tiles)
    int g2 = 256;                         // 1 block/CU (96 KB LDS)

    // workspace layout (4-byte elements)
    float* h       = (float*)d_ws;                    // N*64
    float* pM      = h + (size_t)N * D;               // gS*4160
    float* Mbar    = pM + (size_t)gS * 4160;          // 4160
    float* ss      = Mbar + 4160;                     // 256
    float* embsum  = ss + 256;                        // 60*64
    int*   cnt     = (int*)(embsum + 60 * D);         // N
    int*   offs    = cnt + N;                         // N+1
    int*   bsum    = offs + N + 1;                    // NB
    int*   boff    = bsum + NB;                       // NB
    int*   payload = boff + NB;                       // E

    hipMemsetAsync(cnt, 0, (size_t)N * sizeof(int), stream);

    k_embsum<<<60, 64, 0, stream>>>(be0, be1, be2, embsum);

    int e2 = (E + 1) / 2;
    int eBlocks2 = (e2 + 255) / 256;
    k_hist<<<eBlocks2, 256, 0, stream>>>(ei, cnt, E);
    k_scan1<<<NB, 256, 0, stream>>>(cnt, offs, bsum, N);
    k_scan2<<<1, 128, 0, stream>>>(bsum, boff, NB);
    k_scan3<<<(N + 255) / 256, 256, 0, stream>>>(offs, cnt, boff, N, E);
    k_scatter<<<eBlocks2, 256, 0, stream>>>(ei, ef, cnt, payload, E);

    // two half-range dispatches (profiling visibility; same total work)
    int nHalf = (N + 1) / 2;
    int gR = (nHalf + 3) / 4;
    k_reduce<<<gR, 256, 0, stream>>>(nf, offs, payload, embsum, epsp, h, 0, nHalf);
    k_reduce<<<gR, 256, 0, stream>>>(nf, offs, payload, embsum, epsp, h, nHalf, N);

    k_stats<<<gS, 256, 0, stream>>>(h, pM, N, tilesS);
    k_redM<<<(4160 + 255) / 256, 256, 0, stream>>>(pM, gS, Mbar, 1.0f / (float)N);
    k_bn<<<1, 128, 0, stream>>>(Mbar, W1, b1, gamma, beta, ss);

    k_gemm2<<<g2, 256, 0, stream>>>(h, W1, b1, ss, W2, b2v, out, N, tiles2);
}